// Round 26
// baseline (341.381 us; speedup 1.0000x reference)
//
#include <hip/hip_runtime.h>

#define ROWS 8192
#define KDIM 4096
#define NDIM 4096

typedef float f32x4 __attribute__((ext_vector_type(4)));

// ws layout (floats):
//   w01 : [4096][16]  at 0      (65536)   -- k-major, r2 contiguous
//   w23 : [16][4096]  at 65536  (65536)
//
// R26: R25 (best, 54.6us) + ONE lever, correctly targeted this time:
// grid 1024 -> 2048 via 4-row blocks (grid was capping occupancy at
// 4 blocks/CU; LDS/VGPR never were). 8 blocks/CU = 32 waves/CU doubles
// latency-hiding for phase-1's ~50% stall. Cost: w01/w23 L2 traffic
// doubles (row-independent per block) -- L2 has headroom. acc[4],
// launch_bounds(256,8) pins VGPR <= 64 for the 8-wave/SIMD residency.

__device__ inline f32x4 fma4(float s, f32x4 w, f32x4 a) {
    a.x = fmaf(s, w.x, a.x);
    a.y = fmaf(s, w.y, a.y);
    a.z = fmaf(s, w.z, a.z);
    a.w = fmaf(s, w.w, a.w);
    return a;
}
__device__ inline f32x4 shfl_xor4(f32x4 v, int m) {
    v.x = __shfl_xor(v.x, m, 64);
    v.y = __shfl_xor(v.y, m, 64);
    v.z = __shfl_xor(v.z, m, 64);
    v.w = __shfl_xor(v.w, m, 64);
    return v;
}

// ---------------------------------------------------------------------------
// Build W01 (4096x16, k-major) and W23 (16x4096) from the TT cores.
// ---------------------------------------------------------------------------
__global__ __launch_bounds__(256) void tt_prep(
    const float* __restrict__ c0, const float* __restrict__ c1,
    const float* __restrict__ c2, const float* __restrict__ c3,
    float* __restrict__ w01, float* __restrict__ w23)
{
    int gid = blockIdx.x * 256 + threadIdx.x;  // 0..131071
    if (gid < 65536) {
        int p = gid >> 4, r2 = gid & 15;
        int n0 = p >> 6, n1 = p & 63;
        float s = 0.f;
        #pragma unroll
        for (int r1 = 0; r1 < 16; ++r1)
            s = fmaf(c0[n0 * 16 + r1], c1[(r1 * 64 + n1) * 16 + r2], s);
        w01[gid] = s;
    } else {
        int g = gid - 65536;
        int r2 = g >> 12, j = g & 4095;
        int n2 = j >> 6, n3 = j & 63;
        float s = 0.f;
        #pragma unroll
        for (int r3 = 0; r3 < 16; ++r3)
            s = fmaf(c2[(r2 * 64 + n2) * 16 + r3], c3[r3 * 64 + n3], s);
        w23[g] = s;
    }
}

// ---------------------------------------------------------------------------
// Fused: out[4 rows] = (x[4 rows] @ W01) @ W23 per block. Grid 2048.
// ---------------------------------------------------------------------------
__global__ __launch_bounds__(256, 8) void tt_fused(
    const float* __restrict__ x, const float* __restrict__ w01,
    const float* __restrict__ w23, float* __restrict__ out)
{
    __shared__ __align__(16) float ldsx[4][4][128]; // 8 KB, wave-private chunks
    __shared__ __align__(16) float tsp[4][4][16];   // per-wave partial T
    __shared__ __align__(16) float ts[4][16];       // summed T tile
    const int t = threadIdx.x;
    const int lane = t & 63;
    const int wv = t >> 6;            // wave 0..3: K segment owner
    const int q = lane & 3;           // r2 quad
    const int klane = lane >> 2;      // 0..15
    const int rh = lane >> 5;         // staging row parity (0/1)
    const int cl = (lane & 31) * 4;   // staging column 0..124
    const int row0 = blockIdx.x * 4;
    const int k0 = wv * 1024;

    const float* xb = x + (size_t)row0 * KDIM + k0;
    const float* wb = w01 + (size_t)k0 * 16;

    // ---- Phase 1: LDS-staged broadcast engine. 8 chunks of 128 k.
    f32x4 acc[4];
    #pragma unroll
    for (int r = 0; r < 4; ++r) acc[r] = (f32x4)(0.f);

    #pragma unroll 1
    for (int ch = 0; ch < 8; ++ch) {
        // Stage: 4 rows x 128 k; 2 loads, each two 512 B row segments
        // (1 KB unique per instruction). Wave-private: no barrier.
        f32x4 xs[2];
        #pragma unroll
        for (int i = 0; i < 2; ++i)
            xs[i] = *(const f32x4*)&xb[(size_t)(2 * i + rh) * KDIM + ch * 128 + cl];
        #pragma unroll
        for (int i = 0; i < 2; ++i)
            *(f32x4*)&ldsx[wv][2 * i + rh][cl] = xs[i];

        // Compute: 2 x 64-k iterations; x from LDS broadcast (free),
        // w from L1/L2 (R5-verified mapping).
        #pragma unroll 2
        for (int it = 0; it < 2; ++it) {
            const int kk0 = it * 64 + klane * 4;
            f32x4 wq[4];
            #pragma unroll
            for (int kk = 0; kk < 4; ++kk)
                wq[kk] = *(const f32x4*)&wb[(size_t)(ch * 128 + kk0 + kk) * 16 + q * 4];
            f32x4 xv[4];
            #pragma unroll
            for (int r = 0; r < 4; ++r)
                xv[r] = *(const f32x4*)&ldsx[wv][r][kk0];
            #pragma unroll
            for (int kk = 0; kk < 4; ++kk)
                #pragma unroll
                for (int r = 0; r < 4; ++r)
                    acc[r] = fma4(xv[r][kk], wq[kk], acc[r]);
        }
    }

    // Reduce-scatter butterfly over klane, R5 keep-upper convention for
    // 4 rows: scatter bits 5 (row-bit1), 4 (row-bit0); plain bits 3,2.
    // Lane ends holding row = (lane>>4)&3 for quad q; writers (lane&12)==0.
    const bool b5 = lane & 32, b4 = lane & 16;
    f32x4 s1[2];
    #pragma unroll
    for (int j = 0; j < 2; ++j) {
        f32x4 send = b5 ? acc[j] : acc[2 + j];
        f32x4 keep = b5 ? acc[2 + j] : acc[j];
        s1[j] = keep + shfl_xor4(send, 32);
    }
    f32x4 s2;
    {
        f32x4 send = b4 ? s1[0] : s1[1];
        f32x4 keep = b4 ? s1[1] : s1[0];
        s2 = keep + shfl_xor4(send, 16);
    }
    s2 += shfl_xor4(s2, 8);
    s2 += shfl_xor4(s2, 4);

    if ((lane & 12) == 0) {
        int row = (lane >> 4) & 3;
        *(f32x4*)&tsp[wv][row][q * 4] = s2;
    }
    __syncthreads();

    // Sum the 4 wave partials into ts[4][16].
    if (t < 64) {
        int row = t >> 4, r = t & 15;
        ts[row][r] = tsp[0][row][r] + tsp[1][row][r]
                   + tsp[2][row][r] + tsp[3][row][r];
    }
    __syncthreads();

    // ---- Phase 2: j-sweep, 4 j-tiles of 1024; w[16] in regs, 4 rows.
    const size_t obase = (size_t)row0 * NDIM;
    #pragma unroll 1
    for (int jt = 0; jt < 4; ++jt) {
        const int j0 = jt * 1024 + t * 4;
        f32x4 w[16];
        #pragma unroll
        for (int r = 0; r < 16; ++r)
            w[r] = *(const f32x4*)&w23[r * NDIM + j0];
        #pragma unroll 2
        for (int row = 0; row < 4; ++row) {
            const f32x4* trp = (const f32x4*)&ts[row][0];
            f32x4 t0 = trp[0], t1 = trp[1], t2 = trp[2], t3 = trp[3];
            f32x4 a = (f32x4)(0.f);
            a = fma4(t0.x, w[0],  a); a = fma4(t0.y, w[1],  a);
            a = fma4(t0.z, w[2],  a); a = fma4(t0.w, w[3],  a);
            a = fma4(t1.x, w[4],  a); a = fma4(t1.y, w[5],  a);
            a = fma4(t1.z, w[6],  a); a = fma4(t1.w, w[7],  a);
            a = fma4(t2.x, w[8],  a); a = fma4(t2.y, w[9],  a);
            a = fma4(t2.z, w[10], a); a = fma4(t2.w, w[11], a);
            a = fma4(t3.x, w[12], a); a = fma4(t3.y, w[13], a);
            a = fma4(t3.z, w[14], a); a = fma4(t3.w, w[15], a);
            __builtin_nontemporal_store(a,
                (f32x4*)&out[obase + (size_t)row * NDIM + j0]);
        }
    }
}

extern "C" void kernel_launch(void* const* d_in, const int* in_sizes, int n_in,
                              void* d_out, int out_size, void* d_ws, size_t ws_size,
                              hipStream_t stream) {
    const float* x  = (const float*)d_in[0];
    const float* c0 = (const float*)d_in[1];
    const float* c1 = (const float*)d_in[2];
    const float* c2 = (const float*)d_in[3];
    const float* c3 = (const float*)d_in[4];
    float* out = (float*)d_out;

    float* w01 = (float*)d_ws;
    float* w23 = w01 + 65536;

    tt_prep<<<512, 256, 0, stream>>>(c0, c1, c2, c3, w01, w23);
    tt_fused<<<2048, 256, 0, stream>>>(x, w01, w23, out);
}

// Round 27
// 54.299 us; speedup vs baseline: 6.2870x; 6.2870x over previous
//
#include <hip/hip_runtime.h>

#define ROWS 8192
#define KDIM 4096
#define NDIM 4096

typedef float f32x4 __attribute__((ext_vector_type(4)));

// ws layout (floats):
//   w01 : [4096][16]  at 0      (65536)   -- k-major, r2 contiguous
//   w23 : [16][4096]  at 65536  (65536)
//
// FINAL (= R25, verified 54.64 us best). Fused kernel:
//   phase 1: LDS-staged broadcast engine -- plain coalesced staging loads
//     (1 KB unique/instr) into wave-private LDS; 4-lane broadcast reads
//     from LDS are free; R5-verified butterfly reduce. 8 chunks of 128 k.
//   phase 2: j-sweep, w23[16] f32x4 in regs, NT out-stores.
// Grid 1024 x 256 thr. Ceiling analysis: 268 MB compulsory traffic at
// ~7.1 TB/s duplex = ~38 us floor + 3.5 us prep; this kernel: ~54.6 us.

__device__ inline f32x4 fma4(float s, f32x4 w, f32x4 a) {
    a.x = fmaf(s, w.x, a.x);
    a.y = fmaf(s, w.y, a.y);
    a.z = fmaf(s, w.z, a.z);
    a.w = fmaf(s, w.w, a.w);
    return a;
}
__device__ inline f32x4 shfl_xor4(f32x4 v, int m) {
    v.x = __shfl_xor(v.x, m, 64);
    v.y = __shfl_xor(v.y, m, 64);
    v.z = __shfl_xor(v.z, m, 64);
    v.w = __shfl_xor(v.w, m, 64);
    return v;
}

// ---------------------------------------------------------------------------
// Build W01 (4096x16, k-major) and W23 (16x4096) from the TT cores.
// ---------------------------------------------------------------------------
__global__ __launch_bounds__(256) void tt_prep(
    const float* __restrict__ c0, const float* __restrict__ c1,
    const float* __restrict__ c2, const float* __restrict__ c3,
    float* __restrict__ w01, float* __restrict__ w23)
{
    int gid = blockIdx.x * 256 + threadIdx.x;  // 0..131071
    if (gid < 65536) {
        int p = gid >> 4, r2 = gid & 15;
        int n0 = p >> 6, n1 = p & 63;
        float s = 0.f;
        #pragma unroll
        for (int r1 = 0; r1 < 16; ++r1)
            s = fmaf(c0[n0 * 16 + r1], c1[(r1 * 64 + n1) * 16 + r2], s);
        w01[gid] = s;
    } else {
        int g = gid - 65536;
        int r2 = g >> 12, j = g & 4095;
        int n2 = j >> 6, n3 = j & 63;
        float s = 0.f;
        #pragma unroll
        for (int r3 = 0; r3 < 16; ++r3)
            s = fmaf(c2[(r2 * 64 + n2) * 16 + r3], c3[r3 * 64 + n3], s);
        w23[g] = s;
    }
}

// ---------------------------------------------------------------------------
// Fused: out[8 rows] = (x[8 rows] @ W01) @ W23 per block. Grid 1024.
// ---------------------------------------------------------------------------
__global__ __launch_bounds__(256) void tt_fused(
    const float* __restrict__ x, const float* __restrict__ w01,
    const float* __restrict__ w23, float* __restrict__ out)
{
    __shared__ __align__(16) float ldsx[4][8][128]; // 16 KB, wave-private chunks
    __shared__ __align__(16) float tsp[4][8][16];   // per-wave partial T
    __shared__ __align__(16) float ts[8][16];       // summed T tile
    const int t = threadIdx.x;
    const int lane = t & 63;
    const int wv = t >> 6;            // wave 0..3: K segment owner
    const int q = lane & 3;           // r2 quad
    const int klane = lane >> 2;      // 0..15
    const int rh = lane >> 5;         // staging row parity (0/1)
    const int cl = (lane & 31) * 4;   // staging column 0..124
    const int row0 = blockIdx.x * 8;
    const int k0 = wv * 1024;

    const float* xb = x + (size_t)row0 * KDIM + k0;
    const float* wb = w01 + (size_t)k0 * 16;

    // ---- Phase 1: LDS-staged broadcast engine. 8 chunks of 128 k.
    f32x4 acc[8];
    #pragma unroll
    for (int r = 0; r < 8; ++r) acc[r] = (f32x4)(0.f);

    #pragma unroll 1
    for (int ch = 0; ch < 8; ++ch) {
        // Stage: 8 rows x 128 k; 4 loads, each two 512 B row segments
        // (1 KB unique per instruction). Wave-private: no barrier.
        f32x4 xs[4];
        #pragma unroll
        for (int i = 0; i < 4; ++i)
            xs[i] = *(const f32x4*)&xb[(size_t)(2 * i + rh) * KDIM + ch * 128 + cl];
        #pragma unroll
        for (int i = 0; i < 4; ++i)
            *(f32x4*)&ldsx[wv][2 * i + rh][cl] = xs[i];

        // Compute: 2 x 64-k iterations; x from LDS broadcast (free),
        // w from L1/L2 (R5-verified mapping).
        #pragma unroll 2
        for (int it = 0; it < 2; ++it) {
            const int kk0 = it * 64 + klane * 4;
            f32x4 wq[4];
            #pragma unroll
            for (int kk = 0; kk < 4; ++kk)
                wq[kk] = *(const f32x4*)&wb[(size_t)(ch * 128 + kk0 + kk) * 16 + q * 4];
            f32x4 xv[8];
            #pragma unroll
            for (int r = 0; r < 8; ++r)
                xv[r] = *(const f32x4*)&ldsx[wv][r][kk0];
            #pragma unroll
            for (int kk = 0; kk < 4; ++kk)
                #pragma unroll
                for (int r = 0; r < 8; ++r)
                    acc[r] = fma4(xv[r][kk], wq[kk], acc[r]);
        }
    }

    // R5-verified reduce-scatter butterfly over klane (static indices only).
    const bool b5 = lane & 32, b4 = lane & 16, b3 = lane & 8;
    f32x4 s1[4];
    #pragma unroll
    for (int j = 0; j < 4; ++j) {
        f32x4 send = b5 ? acc[j] : acc[4 + j];
        f32x4 keep = b5 ? acc[4 + j] : acc[j];
        s1[j] = keep + shfl_xor4(send, 32);
    }
    f32x4 s2[2];
    #pragma unroll
    for (int j = 0; j < 2; ++j) {
        f32x4 send = b4 ? s1[j] : s1[2 + j];
        f32x4 keep = b4 ? s1[2 + j] : s1[j];
        s2[j] = keep + shfl_xor4(send, 16);
    }
    f32x4 s3;
    {
        f32x4 send = b3 ? s2[0] : s2[1];
        f32x4 keep = b3 ? s2[1] : s2[0];
        s3 = keep + shfl_xor4(send, 8);
    }
    s3 += shfl_xor4(s3, 4);

    if ((lane & 4) == 0) {
        int row = (lane >> 3) & 7;
        *(f32x4*)&tsp[wv][row][q * 4] = s3;
    }
    __syncthreads();

    // Sum the 4 wave partials into ts[8][16].
    if (t < 128) {
        int row = t >> 4, r = t & 15;
        ts[row][r] = tsp[0][row][r] + tsp[1][row][r]
                   + tsp[2][row][r] + tsp[3][row][r];
    }
    __syncthreads();

    // ---- Phase 2: R5-verified j-sweep. 4 j-tiles of 1024; w[16] in regs.
    const size_t obase = (size_t)row0 * NDIM;
    #pragma unroll 1
    for (int jt = 0; jt < 4; ++jt) {
        const int j0 = jt * 1024 + t * 4;
        f32x4 w[16];
        #pragma unroll
        for (int r = 0; r < 16; ++r)
            w[r] = *(const f32x4*)&w23[r * NDIM + j0];
        #pragma unroll 2
        for (int row = 0; row < 8; ++row) {
            const f32x4* trp = (const f32x4*)&ts[row][0];
            f32x4 t0 = trp[0], t1 = trp[1], t2 = trp[2], t3 = trp[3];
            f32x4 a = (f32x4)(0.f);
            a = fma4(t0.x, w[0],  a); a = fma4(t0.y, w[1],  a);
            a = fma4(t0.z, w[2],  a); a = fma4(t0.w, w[3],  a);
            a = fma4(t1.x, w[4],  a); a = fma4(t1.y, w[5],  a);
            a = fma4(t1.z, w[6],  a); a = fma4(t1.w, w[7],  a);
            a = fma4(t2.x, w[8],  a); a = fma4(t2.y, w[9],  a);
            a = fma4(t2.z, w[10], a); a = fma4(t2.w, w[11], a);
            a = fma4(t3.x, w[12], a); a = fma4(t3.y, w[13], a);
            a = fma4(t3.z, w[14], a); a = fma4(t3.w, w[15], a);
            __builtin_nontemporal_store(a,
                (f32x4*)&out[obase + (size_t)row * NDIM + j0]);
        }
    }
}

extern "C" void kernel_launch(void* const* d_in, const int* in_sizes, int n_in,
                              void* d_out, int out_size, void* d_ws, size_t ws_size,
                              hipStream_t stream) {
    const float* x  = (const float*)d_in[0];
    const float* c0 = (const float*)d_in[1];
    const float* c1 = (const float*)d_in[2];
    const float* c2 = (const float*)d_in[3];
    const float* c3 = (const float*)d_in[4];
    float* out = (float*)d_out;

    float* w01 = (float*)d_ws;
    float* w23 = w01 + 65536;

    tt_prep<<<512, 256, 0, stream>>>(c0, c1, c2, c3, w01, w23);
    tt_fused<<<1024, 256, 0, stream>>>(x, w01, w23, out);
}